// Round 1
// 1382.846 us; speedup vs baseline: 1.0502x; 1.0502x over previous
//
#include <hip/hip_runtime.h>

typedef unsigned short u16;
typedef __attribute__((ext_vector_type(8))) short s8v;
typedef __attribute__((ext_vector_type(4))) float f32x4;

__device__ __forceinline__ u16 f2bf(float f) {
  unsigned int u = __float_as_uint(f);
  u += ((u >> 16) & 1u) + 0x7FFFu;
  return (u16)(u >> 16);
}
__device__ __forceinline__ float bf2f(u16 h) {
  return __uint_as_float(((unsigned int)h) << 16);
}
__device__ __forceinline__ void gl_lds16(const void* g, void* l) {
  __builtin_amdgcn_global_load_lds(
      (__attribute__((address_space(1))) void*)g,
      (__attribute__((address_space(3))) void*)l, 16, 0, 0);
}
__device__ __forceinline__ f32x4 mfma16(s8v a, s8v b, f32x4 c) {
  return __builtin_amdgcn_mfma_f32_16x16x32_bf16(a, b, c, 0, 0, 0);
}

// ---------------- transpose + fp32->bf16 convert: out[c][r] = bf16(in[r][c])
__global__ void transpose_cvt(const float* __restrict__ in, u16* __restrict__ out,
                              int rows, int cols, int ldo) {
  __shared__ float tile[32][33];
  int c0 = blockIdx.x * 32, r0 = blockIdx.y * 32;
  int tx = threadIdx.x, ty = threadIdx.y;  // 32 x 8
#pragma unroll
  for (int i = 0; i < 4; i++)
    tile[ty + i * 8][tx] = in[(long)(r0 + ty + i * 8) * cols + c0 + tx];
  __syncthreads();
#pragma unroll
  for (int i = 0; i < 4; i++)
    out[(long)(c0 + ty + i * 8) * ldo + r0 + tx] = f2bf(tile[tx][ty + i * 8]);
}

// ---------------- V transpose: v_t[b][d][n] = proj[b,n][2176+d] (bf16)
__global__ void vtrans(const u16* __restrict__ proj, u16* __restrict__ v_t) {
  __shared__ u16 tile[32][33];
  int n0 = blockIdx.x * 32, d0 = blockIdx.y * 32, b = blockIdx.z;
  int tx = threadIdx.x, ty = threadIdx.y;  // 32 x 8
#pragma unroll
  for (int i = 0; i < 4; i++)
    tile[ty + i * 8][tx] =
        proj[((long)b * 2048 + n0 + ty + i * 8) * 18688 + 2176 + d0 + tx];
  __syncthreads();
#pragma unroll
  for (int i = 0; i < 4; i++)
    v_t[((long)b * 128 + d0 + ty + i * 8) * 2048 + n0 + tx] = tile[tx][ty + i * 8];
}

// ---------------- fill aug K-cols [2048,2048+naug) of a transposed weight
__global__ void fill_aug_k(u16* __restrict__ wt, int N, int ldo, int naug,
                           const float* __restrict__ bq, const float* __restrict__ bk,
                           const float* __restrict__ bv) {
  long idx = (long)blockIdx.x * 256 + threadIdx.x;
  if (idx >= (long)N * naug) return;
  int n = (int)(idx / naug), j = (int)(idx % naug);
  float v = 0.f;
  if (bq && j < 8 && n < 2048) v = bq[j * 2048 + n];
  else if (bk && j >= 8 && j < 16 && n >= 2048 && n < 2176) v = bk[(j - 8) * 128 + (n - 2048)];
  else if (bv && j >= 16 && j < 24 && n >= 2176 && n < 2304) v = bv[(j - 16) * 128 + (n - 2176)];
  wt[(long)n * ldo + 2048 + j] = f2bf(v);
}

// ---------------- layernorm: x fp32 (4096x2048) -> xn_aug bf16 cols [0,2048), ld 2112
__global__ __launch_bounds__(256) void layernorm_k(const float* __restrict__ x,
                                                   const float* __restrict__ gamma,
                                                   u16* __restrict__ xn) {
  const int row = blockIdx.x, tid = threadIdx.x;
  const float* xr = x + (long)row * 2048 + tid * 8;
  float4 v0 = *(const float4*)xr;
  float4 v1 = *(const float4*)(xr + 4);
  float vals[8] = {v0.x, v0.y, v0.z, v0.w, v1.x, v1.y, v1.z, v1.w};
  float s = 0.f, q = 0.f;
#pragma unroll
  for (int e = 0; e < 8; e++) { s += vals[e]; q += vals[e] * vals[e]; }
#pragma unroll
  for (int off = 32; off > 0; off >>= 1) {
    s += __shfl_down(s, off, 64);
    q += __shfl_down(q, off, 64);
  }
  __shared__ float red[8];
  const int w = tid >> 6, lane = tid & 63;
  if (lane == 0) { red[w] = s; red[4 + w] = q; }
  __syncthreads();
  if (tid == 0) {
    float S = red[0] + red[1] + red[2] + red[3];
    float Q = red[4] + red[5] + red[6] + red[7];
    float mu = S * (1.f / 2048.f);
    float var = Q * (1.f / 2048.f) - mu * mu;
    red[0] = mu; red[1] = rsqrtf(var + 1e-5f);
  }
  __syncthreads();
  float mu = red[0], rs = red[1];
  const float* g = gamma + tid * 8;
  u16 ov[8];
#pragma unroll
  for (int e = 0; e < 8; e++) ov[e] = f2bf((vals[e] - mu) * rs * g[e]);
  *(s8v*)(xn + (long)row * 2112 + tid * 8) = *(const s8v*)ov;
}

// ---------------- t_q|t_k|t_v = xn @ a_* -> bf16 into xn_aug cols [2048,2080); zero [2080,2112)
__global__ __launch_bounds__(256) void lora_down_x(u16* __restrict__ xn_aug,
                                                   const float* __restrict__ aq,
                                                   const float* __restrict__ ak,
                                                   const float* __restrict__ av) {
  const int row = blockIdx.x, tid = threadIdx.x;
  s8v xv = *(const s8v*)(xn_aug + (long)row * 2112 + tid * 8);
  float acc[3][8];
#pragma unroll
  for (int m = 0; m < 3; m++)
#pragma unroll
    for (int j = 0; j < 8; j++) acc[m][j] = 0.f;
  const float* mats[3] = {aq, ak, av};
#pragma unroll
  for (int e = 0; e < 8; e++) {
    float xe = bf2f((u16)xv[e]);
    int k = tid * 8 + e;
#pragma unroll
    for (int m = 0; m < 3; m++) {
      const float4* ap = (const float4*)(mats[m] + (long)k * 8);
      float4 a0 = ap[0], a1 = ap[1];
      acc[m][0] += xe * a0.x; acc[m][1] += xe * a0.y;
      acc[m][2] += xe * a0.z; acc[m][3] += xe * a0.w;
      acc[m][4] += xe * a1.x; acc[m][5] += xe * a1.y;
      acc[m][6] += xe * a1.z; acc[m][7] += xe * a1.w;
    }
  }
#pragma unroll
  for (int m = 0; m < 3; m++)
#pragma unroll
    for (int j = 0; j < 8; j++)
#pragma unroll
      for (int off = 32; off > 0; off >>= 1)
        acc[m][j] += __shfl_down(acc[m][j], off, 64);
  __shared__ float red[4][24];
  const int w = tid >> 6, lane = tid & 63;
  if (lane == 0)
    for (int m = 0; m < 3; m++)
      for (int j = 0; j < 8; j++) red[w][m * 8 + j] = acc[m][j];
  __syncthreads();
  if (tid < 64) {
    float v = 0.f;
    if (tid < 24) v = red[0][tid] + red[1][tid] + red[2][tid] + red[3][tid];
    xn_aug[(long)row * 2112 + 2048 + tid] = f2bf(v);
  }
}

// ---------------- t_o = ctx @ a_o -> bf16 into ctx_aug cols [2048,2080)
__global__ __launch_bounds__(256) void lora_down_ctx(u16* __restrict__ ctx_aug,
                                                     const float* __restrict__ ao) {
  const int row = blockIdx.x, tid = threadIdx.x;
  s8v xv = *(const s8v*)(ctx_aug + (long)row * 2080 + tid * 8);
  float acc[8];
#pragma unroll
  for (int j = 0; j < 8; j++) acc[j] = 0.f;
#pragma unroll
  for (int e = 0; e < 8; e++) {
    float xe = bf2f((u16)xv[e]);
    int k = tid * 8 + e;
    const float4* ap = (const float4*)(ao + (long)k * 8);
    float4 a0 = ap[0], a1 = ap[1];
    acc[0] += xe * a0.x; acc[1] += xe * a0.y; acc[2] += xe * a0.z; acc[3] += xe * a0.w;
    acc[4] += xe * a1.x; acc[5] += xe * a1.y; acc[6] += xe * a1.z; acc[7] += xe * a1.w;
  }
#pragma unroll
  for (int j = 0; j < 8; j++)
#pragma unroll
    for (int off = 32; off > 0; off >>= 1)
      acc[j] += __shfl_down(acc[j], off, 64);
  __shared__ float red[4][8];
  const int w = tid >> 6, lane = tid & 63;
  if (lane == 0)
    for (int j = 0; j < 8; j++) red[w][j] = acc[j];
  __syncthreads();
  if (tid < 32) {
    float v = 0.f;
    if (tid < 8) v = red[0][tid] + red[1][tid] + red[2][tid] + red[3][tid];
    ctx_aug[(long)row * 2080 + 2048 + tid] = f2bf(v);
  }
}

// ---------------- RoPE (+ q scale) in-place on proj cols [0,2048) (q) and [2048,2176) (k)
__global__ void rope_k(u16* __restrict__ proj) {
  int idx = blockIdx.x * 256 + threadIdx.x;  // 4096*17*64
  int i = idx & 63;
  int u = (idx >> 6) % 17;
  int row = idx / (17 * 64);
  int n = row & 2047;
  float invf = __powf(10000.f, -(float)i * (1.f / 64.f));
  float ang = (float)n * invf;
  float cs = cosf(ang), sn = sinf(ang);
  int cb = (u < 16) ? u * 128 : 2048;
  u16* p = proj + (long)row * 18688 + cb + i;
  float t1 = bf2f(p[0]), t2 = bf2f(p[64]);
  float sc = (u < 16) ? 0.08838834764831845f : 1.f;  // 128^-0.5 on q only
  p[0]  = f2bf((t1 * cs - t2 * sn) * sc);
  p[64] = f2bf((t2 * cs + t1 * sn) * sc);
}

// ---------------- h = silu(gate)*x1, in-place into x1 region of proj
__global__ void silu_mul_k(u16* __restrict__ proj) {
  long idx = (long)blockIdx.x * 256 + threadIdx.x;  // 4096*1024
  int row = (int)(idx >> 10);
  int c8 = (int)(idx & 1023) * 8;
  u16* px = proj + (long)row * 18688 + 2304 + c8;
  const u16* pg = proj + (long)row * 18688 + 10496 + c8;
  s8v xv = *(const s8v*)px;
  s8v gv = *(const s8v*)pg;
  u16 ov[8];
#pragma unroll
  for (int e = 0; e < 8; e++) {
    float x1 = bf2f((u16)xv[e]);
    float g = bf2f((u16)gv[e]);
    ov[e] = f2bf(x1 * g / (1.f + __expf(-g)));
  }
  *(s8v*)px = *(const s8v*)ov;
}

// ---------------- legacy 128x128 GEMM: C(MxN) = A(MxK,row,bf16) @ Bt(NxK,row,bf16)^T
// kept for the two narrow output GEMMs (512 blocks -> full-GPU there).
enum { STORE_BF16 = 0, STORE_F32 = 1, ADD_F32 = 2 };
template <int MODE>
__global__ __launch_bounds__(256, 2) void gemm_bt(const u16* __restrict__ A, int lda,
                                                  const u16* __restrict__ Bt, int ldb,
                                                  void* __restrict__ Cv, int ldc, int K,
                                                  int nbx) {
  const int my = blockIdx.x & 31;
  const int mx = blockIdx.y * 8 + (blockIdx.x >> 5);
  if (mx >= nbx) return;
  __shared__ u16 As[128 * 32];
  __shared__ u16 Bs[128 * 32];
  const int tid = threadIdx.x;
  const int w = tid >> 6, lane = tid & 63, quad = lane >> 4, l15 = lane & 15;
  const int wm = (w >> 1) * 64, wn = (w & 1) * 64;
  const long m0 = (long)my * 128;
  const long n0 = (long)mx * 128;

  const int srow = lane >> 2;
  const int scol = (((lane & 3) ^ ((lane >> 3) & 3)) * 8);
  const int cc0 = w * 2, cc1 = cc0 + 1;
  const u16* ga0 = A + (m0 + cc0 * 16 + srow) * lda + scol;
  const u16* ga1 = A + (m0 + cc1 * 16 + srow) * lda + scol;
  const u16* gb0 = Bt + (n0 + cc0 * 16 + srow) * ldb + scol;
  const u16* gb1 = Bt + (n0 + cc1 * 16 + srow) * ldb + scol;
  u16* la0 = As + cc0 * 512;
  u16* la1 = As + cc1 * 512;
  u16* lb0 = Bs + cc0 * 512;
  u16* lb1 = Bs + cc1 * 512;

  const int sseg = (quad ^ ((l15 >> 1) & 3)) * 8;

  f32x4 acc[4][4];
#pragma unroll
  for (int i = 0; i < 4; i++)
#pragma unroll
    for (int j = 0; j < 4; j++) acc[i][j] = {0.f, 0.f, 0.f, 0.f};

  for (int k0 = 0; k0 < K; k0 += 32) {
    gl_lds16(ga0 + k0, la0);
    gl_lds16(ga1 + k0, la1);
    gl_lds16(gb0 + k0, lb0);
    gl_lds16(gb1 + k0, lb1);
    __syncthreads();
    s8v af[4], bf[4];
#pragma unroll
    for (int mi = 0; mi < 4; mi++)
      af[mi] = *(const s8v*)(As + (wm + mi * 16 + l15) * 32 + sseg);
#pragma unroll
    for (int ni = 0; ni < 4; ni++)
      bf[ni] = *(const s8v*)(Bs + (wn + ni * 16 + l15) * 32 + sseg);
#pragma unroll
    for (int mi = 0; mi < 4; mi++)
#pragma unroll
      for (int ni = 0; ni < 4; ni++)
        acc[mi][ni] = mfma16(af[mi], bf[ni], acc[mi][ni]);
    __syncthreads();
  }
#pragma unroll
  for (int mi = 0; mi < 4; mi++)
#pragma unroll
    for (int r = 0; r < 4; r++) {
      long row = m0 + wm + mi * 16 + quad * 4 + r;
#pragma unroll
      for (int ni = 0; ni < 4; ni++) {
        long col = n0 + wn + ni * 16 + l15;
        float v = acc[mi][ni][r];
        if (MODE == STORE_BF16) ((u16*)Cv)[row * ldc + col] = f2bf(v);
        else if (MODE == STORE_F32) ((float*)Cv)[row * ldc + col] = v;
        else ((float*)Cv)[row * ldc + col] += v;
      }
    }
}

// ================= 256x256 8-phase GEMM (T2+T3+T4+T5), big projection only.
// C(4096 x N) = A(4096 x 2112, ld 2112) @ Bt(N x 2112, ld 2112)^T, C bf16 ld 18688.
// K = 2112, NT = K/64 = 33 (must be odd, >= 3). Grid = 16 * (N/256) 1D, 512 thr.
// LDS 128 KiB: buf b in sh[b*32768 .. ) : A chunk kk (256r x 32k) at +kk*8192,
// B at +16384 likewise. Within a 32k chunk, 8-elem segment s of row r stored at
// s ^ ((r>>1)&3) (2-way bank aliasing only = free). Staged via global_load_lds
// with pre-swizzled global source (linear LDS dest).
// Schedule per K-tile t (cur=t&1): 4 phases, phase (kk,mh):
//   {8|4 ds_read_b128 ; stage unit (kk,mh) of tile t+1 ; s_barrier ;
//    setprio(1) ; 16 MFMA (m-half mh x 4n, 32k) ; setprio(0) ; [vmcnt] ; s_barrier}
// vmcnt(4) at end of phases 1 and 3 (never 0 in steady state). Invariant: a wave
// has <=8 gl_lds in flight; the 4 drained by each wait are exactly the half-K
// units (kk) the next two phases read; the trailing raw s_barrier publishes them.
__global__ __launch_bounds__(512, 2) void gemm256_bt(const u16* __restrict__ A,
                                                     const u16* __restrict__ Bt,
                                                     u16* __restrict__ C, int K) {
  __shared__ u16 sh[65536];
  const int cpx = gridDim.x >> 3;  // gridDim.x % 8 == 0
  const int swz = (blockIdx.x & 7) * cpx + (blockIdx.x >> 3);
  const int bm = swz & 15;   // M/256 = 16 fixed
  const int bn = swz >> 4;
  const int tid = threadIdx.x;
  const int w = tid >> 6, lane = tid & 63;
  const int quad = lane >> 4, l15 = lane & 15;
  const int wm = w >> 2, wn = w & 3;  // 2M x 4N waves
  const int rseg = (quad ^ ((l15 >> 1) & 3)) * 8;
  const int aoff = (wm * 128 + l15) * 32 + rseg;
  const int boff = (wn * 64 + l15) * 32 + rseg;
  const int srow = lane >> 2;
  const int sseg = ((lane & 3) ^ ((lane >> 3) & 3)) * 8;
  const u16* aSrc = A + (long)(bm * 256 + w * 16 + srow) * 2112 + sseg;
  const u16* bSrc = Bt + (long)(bn * 256 + w * 16 + srow) * 2112 + sseg;
  u16* stW = sh + w * 512;  // wave-uniform LDS staging base (+unit offsets)
  const int NT = K >> 6;

  f32x4 acc[8][4];
#pragma unroll
  for (int i = 0; i < 8; i++)
#pragma unroll
    for (int j = 0; j < 4; j++) acc[i][j] = {0.f, 0.f, 0.f, 0.f};

  // prologue: stage tile 0 into buf 0, order kk0h0,kk0h1,kk1h0,kk1h1 (A,B each)
  gl_lds16(aSrc, stW);
  gl_lds16(bSrc, stW + 16384);
  gl_lds16(aSrc + 128L * 2112, stW + 4096);
  gl_lds16(bSrc + 128L * 2112, stW + 16384 + 4096);
  gl_lds16(aSrc + 32, stW + 8192);
  gl_lds16(bSrc + 32, stW + 16384 + 8192);
  gl_lds16(aSrc + 128L * 2112 + 32, stW + 8192 + 4096);
  gl_lds16(bSrc + 128L * 2112 + 32, stW + 16384 + 8192 + 4096);
  asm volatile("s_waitcnt vmcnt(4)" ::: "memory");
  __builtin_amdgcn_s_barrier();

  s8v bf[4];
  int kcol = 64;  // staging column of tile t+1

#define STAGE_UNIT(CUR, KK, MH)                                               \
  gl_lds16(aSrc + (MH) * (128L * 2112) + kcol + (KK) * 32,                    \
           stW + (((CUR) ^ 1) * 32768) + (KK) * 8192 + (MH) * 4096);          \
  gl_lds16(bSrc + (MH) * (128L * 2112) + kcol + (KK) * 32,                    \
           stW + (((CUR) ^ 1) * 32768) + 16384 + (KK) * 8192 + (MH) * 4096);

#define PHASE(CUR, KK, MH, DOB, STG, VM)                                      \
  {                                                                           \
    const u16* Ab = sh + (CUR) * 32768 + (KK) * 8192 + aoff + (MH) * 2048;    \
    s8v af0 = *(const s8v*)(Ab);                                              \
    s8v af1 = *(const s8v*)(Ab + 512);                                        \
    s8v af2 = *(const s8v*)(Ab + 1024);                                       \
    s8v af3 = *(const s8v*)(Ab + 1536);                                       \
    if (DOB) {                                                                \
      const u16* Bb = sh + (CUR) * 32768 + 16384 + (KK) * 8192 + boff;        \
      bf[0] = *(const s8v*)(Bb);                                              \
      bf[1] = *(const s8v*)(Bb + 512);                                        \
      bf[2] = *(const s8v*)(Bb + 1024);                                       \
      bf[3] = *(const s8v*)(Bb + 1536);                                       \
    }                                                                         \
    if (STG) { STAGE_UNIT(CUR, KK, MH) }                                      \
    __builtin_amdgcn_s_barrier();                                             \
    __builtin_amdgcn_s_setprio(1);                                            \
    _Pragma("unroll") for (int ni = 0; ni < 4; ni++) {                        \
      acc[(MH) * 4 + 0][ni] = mfma16(af0, bf[ni], acc[(MH) * 4 + 0][ni]);     \
      acc[(MH) * 4 + 1][ni] = mfma16(af1, bf[ni], acc[(MH) * 4 + 1][ni]);     \
      acc[(MH) * 4 + 2][ni] = mfma16(af2, bf[ni], acc[(MH) * 4 + 2][ni]);     \
      acc[(MH) * 4 + 3][ni] = mfma16(af3, bf[ni], acc[(MH) * 4 + 3][ni]);     \
    }                                                                         \
    __builtin_amdgcn_s_setprio(0);                                            \
    if ((VM) == 4) asm volatile("s_waitcnt vmcnt(4)" ::: "memory");           \
    if ((VM) == 0) asm volatile("s_waitcnt vmcnt(0)" ::: "memory");           \
    __builtin_amdgcn_s_barrier();                                             \
  }

#define TILE(CUR, STG, VM1, VM3)   \
  PHASE(CUR, 0, 0, 1, STG, -1)     \
  PHASE(CUR, 0, 1, 0, STG, VM1)    \
  PHASE(CUR, 1, 0, 1, STG, -1)     \
  PHASE(CUR, 1, 1, 0, STG, VM3)    \
  kcol += 64;

  for (int t2 = 0; t2 < NT - 1; t2 += 2) {
    TILE(0, 1, 4, 4)
    TILE(1, 1, 4, 4)
  }
  // epilogue tile (NT odd -> cur = 0); its kk1 halves drain with vmcnt(0)
  TILE(0, 0, 0, -1)

#undef TILE
#undef PHASE
#undef STAGE_UNIT

  const long m0 = (long)bm * 256 + wm * 128;
  const long n0 = (long)bn * 256 + wn * 64;
#pragma unroll
  for (int mi = 0; mi < 8; mi++)
#pragma unroll
    for (int r = 0; r < 4; r++) {
      long row = m0 + mi * 16 + quad * 4 + r;
#pragma unroll
      for (int ni = 0; ni < 4; ni++) {
        long col = n0 + ni * 16 + l15;
        C[row * 18688 + col] = f2bf(acc[mi][ni][r]);
      }
    }
}

// ---------------- causal flash attention (MQA): K from proj, V from v_t (pre-transposed)
__global__ __launch_bounds__(256) void flash_k(const u16* __restrict__ proj,
                                               const u16* __restrict__ v_t,
                                               u16* __restrict__ ctx) {
  __shared__ u16 Kt[4 * 1024];
  __shared__ u16 Vx[8 * 512];
  __shared__ u16 Pw[4 * 512];
  const int qt = blockIdx.x, h = blockIdx.y, b = blockIdx.z;
  const int tid = threadIdx.x;
  const int w = tid >> 6, lane = tid & 63, quad = lane >> 4, l15 = lane & 15;
  const int qbase = qt * 64 + w * 16;

  s8v qf[4];
  {
    long rowQ = (long)b * 2048 + qbase + l15;
    const u16* qp = proj + rowQ * 18688 + h * 128 + quad * 8;
#pragma unroll
    for (int kk = 0; kk < 4; kk++) qf[kk] = *(const s8v*)(qp + kk * 32);
  }
  f32x4 o[8];
#pragma unroll
  for (int i = 0; i < 8; i++) o[i] = {0.f, 0.f, 0.f, 0.f};
  float m_i[4] = {-1e30f, -1e30f, -1e30f, -1e30f};
  float l_i[4] = {0.f, 0.f, 0.f, 0.f};

  const int srow = lane >> 2;
  const int sseg = ((lane & 3) ^ ((lane >> 3) & 3)) * 8;
  const int rseg = (quad ^ ((l15 >> 1) & 3)) * 8;

  const int nkb = 2 * qt + 2;
  for (int kb = 0; kb < nkb; kb++) {
    const int k0 = kb * 32;
    {
      long rK = (long)b * 2048 + k0;
#pragma unroll
      for (int h2 = 0; h2 < 2; h2++)
        gl_lds16(proj + (rK + h2 * 16 + srow) * 18688 + 2048 + w * 32 + sseg,
                 Kt + w * 1024 + h2 * 512);
#pragma unroll
      for (int h2 = 0; h2 < 2; h2++)
        gl_lds16(v_t + ((long)b * 128 + w * 32 + h2 * 16 + srow) * 2048 + k0 + sseg,
                 Vx + (w * 2 + h2) * 512);
    }
    __syncthreads();
    if (k0 <= qbase + 15) {
      f32x4 s[2];
#pragma unroll
      for (int ni = 0; ni < 2; ni++) {
        f32x4 a = {0.f, 0.f, 0.f, 0.f};
#pragma unroll
        for (int kk = 0; kk < 4; kk++) {
          s8v kf = *(const s8v*)(Kt + kk * 1024 + (ni * 16 + l15) * 32 + rseg);
          a = mfma16(qf[kk], kf, a);
        }
        s[ni] = a;
      }
#pragma unroll
      for (int ni = 0; ni < 2; ni++) {
        int kg = k0 + ni * 16 + l15;
#pragma unroll
        for (int r = 0; r < 4; r++)
          if (kg > qbase + quad * 4 + r) s[ni][r] = -1e30f;
      }
      float al[4];
#pragma unroll
      for (int r = 0; r < 4; r++) {
        float mx = fmaxf(s[0][r], s[1][r]);
#pragma unroll
        for (int off = 8; off > 0; off >>= 1)
          mx = fmaxf(mx, __shfl_xor(mx, off, 16));
        float mn = fmaxf(m_i[r], mx);
        al[r] = __expf(m_i[r] - mn);
        m_i[r] = mn;
      }
#pragma unroll
      for (int ni = 0; ni < 2; ni++)
#pragma unroll
        for (int r = 0; r < 4; r++) s[ni][r] = __expf(s[ni][r] - m_i[r]);
#pragma unroll
      for (int r = 0; r < 4; r++) {
        float rs = s[0][r] + s[1][r];
#pragma unroll
        for (int off = 8; off > 0; off >>= 1)
          rs += __shfl_xor(rs, off, 16);
        l_i[r] = l_i[r] * al[r] + rs;
      }
#pragma unroll
      for (int ni = 0; ni < 2; ni++)
#pragma unroll
        for (int r = 0; r < 4; r++) {
          int p = quad * 4 + r;
          int sg = ni * 2 + (l15 >> 3);
          int sp = sg ^ ((p >> 1) & 3);
          Pw[w * 512 + p * 32 + sp * 8 + (l15 & 7)] = f2bf(s[ni][r]);
        }
      __asm__ volatile("s_waitcnt lgkmcnt(0)" ::: "memory");
#pragma unroll
      for (int nt = 0; nt < 8; nt++)
#pragma unroll
        for (int r = 0; r < 4; r++) o[nt][r] *= al[r];
      s8v pf = *(const s8v*)(Pw + w * 512 + l15 * 32 + rseg);
#pragma unroll
      for (int nt = 0; nt < 8; nt++) {
        s8v vf = *(const s8v*)(Vx + (nt * 16 + l15) * 32 + rseg);
        o[nt] = mfma16(pf, vf, o[nt]);
      }
    }
    __syncthreads();
  }
  float inv[4];
#pragma unroll
  for (int r = 0; r < 4; r++) inv[r] = 1.f / l_i[r];
#pragma unroll
  for (int nt = 0; nt < 8; nt++)
#pragma unroll
    for (int r = 0; r < 4; r++) {
      long row = (long)b * 2048 + qbase + quad * 4 + r;
      ctx[row * 2080 + h * 128 + nt * 16 + l15] = f2bf(o[nt][r] * inv[r]);
    }
}

// ---------------- workspace layout (bytes)
// wf_t is dead after the big GEMM -> its region is reused for ctx_aug.
#define OFF_WF   0L                       // wf_t 18688x2112 bf16 = 78,938,112 ; later ctx_aug (17,039,360)
#define OFF_WO   78938112L                // wo_t 2048x2080 bf16  =  8,519,680
#define OFF_WFF  87457792L                // wff_t 2048x8192 bf16 = 33,554,432
#define OFF_XN   121012224L               // xn_aug 4096x2112 bf16 = 17,301,504 (reused as v_t)
#define OFF_PROJ 138313728L               // proj 4096x18688 bf16 = 153,092,096
#define WS_NEED  291405824L

extern "C" void kernel_launch(void* const* d_in, const int* in_sizes, int n_in,
                              void* d_out, int out_size, void* d_ws, size_t ws_size,
                              hipStream_t stream) {
  const float* x       = (const float*)d_in[0];
  const float* gamma   = (const float*)d_in[1];
  const float* w_fused = (const float*)d_in[2];
  const float* w_attn  = (const float*)d_in[3];
  const float* w_ff    = (const float*)d_in[4];
  const float* a_q = (const float*)d_in[5];
  const float* b_q = (const float*)d_in[6];
  const float* a_k = (const float*)d_in[7];
  const float* b_k = (const float*)d_in[8];
  const float* a_v = (const float*)d_in[9];
  const float* b_v = (const float*)d_in[10];
  const float* a_o = (const float*)d_in[11];
  const float* b_o = (const float*)d_in[12];
  float* out = (float*)d_out;
  if (ws_size < (size_t)WS_NEED) return;

  char* ws = (char*)d_ws;
  u16* wf_t    = (u16*)(ws + OFF_WF);
  u16* ctx_aug = (u16*)(ws + OFF_WF);  // reuses wf_t region after big GEMM
  u16* wo_t    = (u16*)(ws + OFF_WO);
  u16* wff_t   = (u16*)(ws + OFF_WFF);
  u16* xn_aug  = (u16*)(ws + OFF_XN);
  u16* v_t     = (u16*)(ws + OFF_XN);  // reuses xn_aug region after big GEMM
  u16* proj    = (u16*)(ws + OFF_PROJ);

  dim3 tb(32, 8);
  transpose_cvt<<<dim3(18688 / 32, 2048 / 32), tb, 0, stream>>>(w_fused, wf_t, 2048, 18688, 2112);
  transpose_cvt<<<dim3(2048 / 32, 2048 / 32), tb, 0, stream>>>(w_attn, wo_t, 2048, 2048, 2080);
  transpose_cvt<<<dim3(2048 / 32, 8192 / 32), tb, 0, stream>>>(w_ff, wff_t, 8192, 2048, 8192);
  fill_aug_k<<<(18688 * 64 + 255) / 256, 256, 0, stream>>>(wf_t, 18688, 2112, 64, b_q, b_k, b_v);
  fill_aug_k<<<(2048 * 32 + 255) / 256, 256, 0, stream>>>(wo_t, 2048, 2080, 32, b_o, nullptr, nullptr);

  layernorm_k<<<4096, 256, 0, stream>>>(x, gamma, xn_aug);
  lora_down_x<<<4096, 256, 0, stream>>>(xn_aug, a_q, a_k, a_v);

  // proj = xn_aug @ wf_t^T  (q|k|v|x1|gate with QKV-LoRA folded into K-aug, K padded to 2112)
  gemm256_bt<<<dim3(16 * (18688 / 256)), 512, 0, stream>>>(xn_aug, wf_t, proj, 2112);

  rope_k<<<(4096 * 17 * 64) / 256, 256, 0, stream>>>(proj);
  silu_mul_k<<<(4096 * 1024) / 256, 256, 0, stream>>>(proj);
  vtrans<<<dim3(64, 4, 2), tb, 0, stream>>>(proj, v_t);

  flash_k<<<dim3(32, 16, 2), 256, 0, stream>>>(proj, v_t, ctx_aug);
  lora_down_ctx<<<4096, 256, 0, stream>>>(ctx_aug, a_o);

  // d_out = ctx_aug @ wo_t^T (o-LoRA folded), then += h @ wff_t^T
  gemm_bt<STORE_F32><<<dim3(256, 2), 256, 0, stream>>>(
      ctx_aug, 2080, wo_t, 2080, out, 2048, 2080, 16);
  gemm_bt<ADD_F32><<<dim3(256, 2), 256, 0, stream>>>(
      proj + 2304, 18688, wff_t, 8192, out, 2048, 8192, 16);
}

// Round 2
// 1372.201 us; speedup vs baseline: 1.0583x; 1.0078x over previous
//
#include <hip/hip_runtime.h>

typedef unsigned short u16;
typedef __attribute__((ext_vector_type(8))) short s8v;
typedef __attribute__((ext_vector_type(4))) float f32x4;

__device__ __forceinline__ u16 f2bf(float f) {
  unsigned int u = __float_as_uint(f);
  u += ((u >> 16) & 1u) + 0x7FFFu;
  return (u16)(u >> 16);
}
__device__ __forceinline__ float bf2f(u16 h) {
  return __uint_as_float(((unsigned int)h) << 16);
}
__device__ __forceinline__ void gl_lds16(const void* g, void* l) {
  __builtin_amdgcn_global_load_lds(
      (__attribute__((address_space(1))) void*)g,
      (__attribute__((address_space(3))) void*)l, 16, 0, 0);
}
__device__ __forceinline__ f32x4 mfma16(s8v a, s8v b, f32x4 c) {
  return __builtin_amdgcn_mfma_f32_16x16x32_bf16(a, b, c, 0, 0, 0);
}

// ---------------- transpose + fp32->bf16 convert: out[c][r] = bf16(in[r][c])
__global__ void transpose_cvt(const float* __restrict__ in, u16* __restrict__ out,
                              int rows, int cols, int ldo) {
  __shared__ float tile[32][33];
  int c0 = blockIdx.x * 32, r0 = blockIdx.y * 32;
  int tx = threadIdx.x, ty = threadIdx.y;  // 32 x 8
#pragma unroll
  for (int i = 0; i < 4; i++)
    tile[ty + i * 8][tx] = in[(long)(r0 + ty + i * 8) * cols + c0 + tx];
  __syncthreads();
#pragma unroll
  for (int i = 0; i < 4; i++)
    out[(long)(c0 + ty + i * 8) * ldo + r0 + tx] = f2bf(tile[tx][ty + i * 8]);
}

// ---------------- V transpose: v_t[b][d][n] = proj[b,n][2176+d] (bf16)
__global__ void vtrans(const u16* __restrict__ proj, u16* __restrict__ v_t) {
  __shared__ u16 tile[32][33];
  int n0 = blockIdx.x * 32, d0 = blockIdx.y * 32, b = blockIdx.z;
  int tx = threadIdx.x, ty = threadIdx.y;  // 32 x 8
#pragma unroll
  for (int i = 0; i < 4; i++)
    tile[ty + i * 8][tx] =
        proj[((long)b * 2048 + n0 + ty + i * 8) * 18688 + 2176 + d0 + tx];
  __syncthreads();
#pragma unroll
  for (int i = 0; i < 4; i++)
    v_t[((long)b * 128 + d0 + ty + i * 8) * 2048 + n0 + tx] = tile[tx][ty + i * 8];
}

// ---------------- fill aug K-cols [2048,2048+naug) of a transposed weight
__global__ void fill_aug_k(u16* __restrict__ wt, int N, int ldo, int naug,
                           const float* __restrict__ bq, const float* __restrict__ bk,
                           const float* __restrict__ bv) {
  long idx = (long)blockIdx.x * 256 + threadIdx.x;
  if (idx >= (long)N * naug) return;
  int n = (int)(idx / naug), j = (int)(idx % naug);
  float v = 0.f;
  if (bq && j < 8 && n < 2048) v = bq[j * 2048 + n];
  else if (bk && j >= 8 && j < 16 && n >= 2048 && n < 2176) v = bk[(j - 8) * 128 + (n - 2048)];
  else if (bv && j >= 16 && j < 24 && n >= 2176 && n < 2304) v = bv[(j - 16) * 128 + (n - 2176)];
  wt[(long)n * ldo + 2048 + j] = f2bf(v);
}

// ---------------- layernorm: x fp32 (4096x2048) -> xn_aug bf16 cols [0,2048), ld 2112
__global__ __launch_bounds__(256) void layernorm_k(const float* __restrict__ x,
                                                   const float* __restrict__ gamma,
                                                   u16* __restrict__ xn) {
  const int row = blockIdx.x, tid = threadIdx.x;
  const float* xr = x + (long)row * 2048 + tid * 8;
  float4 v0 = *(const float4*)xr;
  float4 v1 = *(const float4*)(xr + 4);
  float vals[8] = {v0.x, v0.y, v0.z, v0.w, v1.x, v1.y, v1.z, v1.w};
  float s = 0.f, q = 0.f;
#pragma unroll
  for (int e = 0; e < 8; e++) { s += vals[e]; q += vals[e] * vals[e]; }
#pragma unroll
  for (int off = 32; off > 0; off >>= 1) {
    s += __shfl_down(s, off, 64);
    q += __shfl_down(q, off, 64);
  }
  __shared__ float red[8];
  const int w = tid >> 6, lane = tid & 63;
  if (lane == 0) { red[w] = s; red[4 + w] = q; }
  __syncthreads();
  if (tid == 0) {
    float S = red[0] + red[1] + red[2] + red[3];
    float Q = red[4] + red[5] + red[6] + red[7];
    float mu = S * (1.f / 2048.f);
    float var = Q * (1.f / 2048.f) - mu * mu;
    red[0] = mu; red[1] = rsqrtf(var + 1e-5f);
  }
  __syncthreads();
  float mu = red[0], rs = red[1];
  const float* g = gamma + tid * 8;
  u16 ov[8];
#pragma unroll
  for (int e = 0; e < 8; e++) ov[e] = f2bf((vals[e] - mu) * rs * g[e]);
  *(s8v*)(xn + (long)row * 2112 + tid * 8) = *(const s8v*)ov;
}

// ---------------- t_q|t_k|t_v = xn @ a_* -> bf16 into xn_aug cols [2048,2080); zero [2080,2112)
__global__ __launch_bounds__(256) void lora_down_x(u16* __restrict__ xn_aug,
                                                   const float* __restrict__ aq,
                                                   const float* __restrict__ ak,
                                                   const float* __restrict__ av) {
  const int row = blockIdx.x, tid = threadIdx.x;
  s8v xv = *(const s8v*)(xn_aug + (long)row * 2112 + tid * 8);
  float acc[3][8];
#pragma unroll
  for (int m = 0; m < 3; m++)
#pragma unroll
    for (int j = 0; j < 8; j++) acc[m][j] = 0.f;
  const float* mats[3] = {aq, ak, av};
#pragma unroll
  for (int e = 0; e < 8; e++) {
    float xe = bf2f((u16)xv[e]);
    int k = tid * 8 + e;
#pragma unroll
    for (int m = 0; m < 3; m++) {
      const float4* ap = (const float4*)(mats[m] + (long)k * 8);
      float4 a0 = ap[0], a1 = ap[1];
      acc[m][0] += xe * a0.x; acc[m][1] += xe * a0.y;
      acc[m][2] += xe * a0.z; acc[m][3] += xe * a0.w;
      acc[m][4] += xe * a1.x; acc[m][5] += xe * a1.y;
      acc[m][6] += xe * a1.z; acc[m][7] += xe * a1.w;
    }
  }
#pragma unroll
  for (int m = 0; m < 3; m++)
#pragma unroll
    for (int j = 0; j < 8; j++)
#pragma unroll
      for (int off = 32; off > 0; off >>= 1)
        acc[m][j] += __shfl_down(acc[m][j], off, 64);
  __shared__ float red[4][24];
  const int w = tid >> 6, lane = tid & 63;
  if (lane == 0)
    for (int m = 0; m < 3; m++)
      for (int j = 0; j < 8; j++) red[w][m * 8 + j] = acc[m][j];
  __syncthreads();
  if (tid < 64) {
    float v = 0.f;
    if (tid < 24) v = red[0][tid] + red[1][tid] + red[2][tid] + red[3][tid];
    xn_aug[(long)row * 2112 + 2048 + tid] = f2bf(v);
  }
}

// ---------------- t_o = ctx @ a_o -> bf16 into ctx_aug cols [2048,2080)
__global__ __launch_bounds__(256) void lora_down_ctx(u16* __restrict__ ctx_aug,
                                                     const float* __restrict__ ao) {
  const int row = blockIdx.x, tid = threadIdx.x;
  s8v xv = *(const s8v*)(ctx_aug + (long)row * 2080 + tid * 8);
  float acc[8];
#pragma unroll
  for (int j = 0; j < 8; j++) acc[j] = 0.f;
#pragma unroll
  for (int e = 0; e < 8; e++) {
    float xe = bf2f((u16)xv[e]);
    int k = tid * 8 + e;
    const float4* ap = (const float4*)(ao + (long)k * 8);
    float4 a0 = ap[0], a1 = ap[1];
    acc[0] += xe * a0.x; acc[1] += xe * a0.y; acc[2] += xe * a0.z; acc[3] += xe * a0.w;
    acc[4] += xe * a1.x; acc[5] += xe * a1.y; acc[6] += xe * a1.z; acc[7] += xe * a1.w;
  }
#pragma unroll
  for (int j = 0; j < 8; j++)
#pragma unroll
    for (int off = 32; off > 0; off >>= 1)
      acc[j] += __shfl_down(acc[j], off, 64);
  __shared__ float red[4][8];
  const int w = tid >> 6, lane = tid & 63;
  if (lane == 0)
    for (int j = 0; j < 8; j++) red[w][j] = acc[j];
  __syncthreads();
  if (tid < 32) {
    float v = 0.f;
    if (tid < 8) v = red[0][tid] + red[1][tid] + red[2][tid] + red[3][tid];
    ctx_aug[(long)row * 2080 + 2048 + tid] = f2bf(v);
  }
}

// ---------------- RoPE (+ q scale) in-place on proj cols [0,2048) (q) and [2048,2176) (k)
__global__ void rope_k(u16* __restrict__ proj) {
  int idx = blockIdx.x * 256 + threadIdx.x;  // 4096*17*64
  int i = idx & 63;
  int u = (idx >> 6) % 17;
  int row = idx / (17 * 64);
  int n = row & 2047;
  float invf = __powf(10000.f, -(float)i * (1.f / 64.f));
  float ang = (float)n * invf;
  float cs = cosf(ang), sn = sinf(ang);
  int cb = (u < 16) ? u * 128 : 2048;
  u16* p = proj + (long)row * 18688 + cb + i;
  float t1 = bf2f(p[0]), t2 = bf2f(p[64]);
  float sc = (u < 16) ? 0.08838834764831845f : 1.f;  // 128^-0.5 on q only
  p[0]  = f2bf((t1 * cs - t2 * sn) * sc);
  p[64] = f2bf((t2 * cs + t1 * sn) * sc);
}

// ---------------- h = silu(gate)*x1, in-place into x1 region of proj
__global__ void silu_mul_k(u16* __restrict__ proj) {
  long idx = (long)blockIdx.x * 256 + threadIdx.x;  // 4096*1024
  int row = (int)(idx >> 10);
  int c8 = (int)(idx & 1023) * 8;
  u16* px = proj + (long)row * 18688 + 2304 + c8;
  const u16* pg = proj + (long)row * 18688 + 10496 + c8;
  s8v xv = *(const s8v*)px;
  s8v gv = *(const s8v*)pg;
  u16 ov[8];
#pragma unroll
  for (int e = 0; e < 8; e++) {
    float x1 = bf2f((u16)xv[e]);
    float g = bf2f((u16)gv[e]);
    ov[e] = f2bf(x1 * g / (1.f + __expf(-g)));
  }
  *(s8v*)px = *(const s8v*)ov;
}

// ---------------- legacy 128x128 GEMM: C(MxN) = A(MxK,row,bf16) @ Bt(NxK,row,bf16)^T
// kept for the two narrow output GEMMs (512 blocks -> full-GPU there).
enum { STORE_BF16 = 0, STORE_F32 = 1, ADD_F32 = 2 };
template <int MODE>
__global__ __launch_bounds__(256, 2) void gemm_bt(const u16* __restrict__ A, int lda,
                                                  const u16* __restrict__ Bt, int ldb,
                                                  void* __restrict__ Cv, int ldc, int K,
                                                  int nbx) {
  const int my = blockIdx.x & 31;
  const int mx = blockIdx.y * 8 + (blockIdx.x >> 5);
  if (mx >= nbx) return;
  __shared__ u16 As[128 * 32];
  __shared__ u16 Bs[128 * 32];
  const int tid = threadIdx.x;
  const int w = tid >> 6, lane = tid & 63, quad = lane >> 4, l15 = lane & 15;
  const int wm = (w >> 1) * 64, wn = (w & 1) * 64;
  const long m0 = (long)my * 128;
  const long n0 = (long)mx * 128;

  const int srow = lane >> 2;
  const int scol = (((lane & 3) ^ ((lane >> 3) & 3)) * 8);
  const int cc0 = w * 2, cc1 = cc0 + 1;
  const u16* ga0 = A + (m0 + cc0 * 16 + srow) * lda + scol;
  const u16* ga1 = A + (m0 + cc1 * 16 + srow) * lda + scol;
  const u16* gb0 = Bt + (n0 + cc0 * 16 + srow) * ldb + scol;
  const u16* gb1 = Bt + (n0 + cc1 * 16 + srow) * ldb + scol;
  u16* la0 = As + cc0 * 512;
  u16* la1 = As + cc1 * 512;
  u16* lb0 = Bs + cc0 * 512;
  u16* lb1 = Bs + cc1 * 512;

  const int sseg = (quad ^ ((l15 >> 1) & 3)) * 8;

  f32x4 acc[4][4];
#pragma unroll
  for (int i = 0; i < 4; i++)
#pragma unroll
    for (int j = 0; j < 4; j++) acc[i][j] = {0.f, 0.f, 0.f, 0.f};

  for (int k0 = 0; k0 < K; k0 += 32) {
    gl_lds16(ga0 + k0, la0);
    gl_lds16(ga1 + k0, la1);
    gl_lds16(gb0 + k0, lb0);
    gl_lds16(gb1 + k0, lb1);
    __syncthreads();
    s8v af[4], bf[4];
#pragma unroll
    for (int mi = 0; mi < 4; mi++)
      af[mi] = *(const s8v*)(As + (wm + mi * 16 + l15) * 32 + sseg);
#pragma unroll
    for (int ni = 0; ni < 4; ni++)
      bf[ni] = *(const s8v*)(Bs + (wn + ni * 16 + l15) * 32 + sseg);
#pragma unroll
    for (int mi = 0; mi < 4; mi++)
#pragma unroll
      for (int ni = 0; ni < 4; ni++)
        acc[mi][ni] = mfma16(af[mi], bf[ni], acc[mi][ni]);
    __syncthreads();
  }
#pragma unroll
  for (int mi = 0; mi < 4; mi++)
#pragma unroll
    for (int r = 0; r < 4; r++) {
      long row = m0 + wm + mi * 16 + quad * 4 + r;
#pragma unroll
      for (int ni = 0; ni < 4; ni++) {
        long col = n0 + wn + ni * 16 + l15;
        float v = acc[mi][ni][r];
        if (MODE == STORE_BF16) ((u16*)Cv)[row * ldc + col] = f2bf(v);
        else if (MODE == STORE_F32) ((float*)Cv)[row * ldc + col] = v;
        else ((float*)Cv)[row * ldc + col] += v;
      }
    }
}

// ================= 256x256 deep-pipelined GEMM (T2+T3+T4+T5), big projection only.
// C(4096 x 18688) = A(4096 x 2112, ld 2112) @ Bt(18688 x 2112, ld 2112)^T, C bf16 ld 18688.
// K = 2112 fixed -> 66 K-tiles of 32. Grid = 16*73 = 1168 (1D), 512 threads.
// LDS: 4-deep ring of 32KB buffers (128 KiB total). buf i at sh + i*16384 (u16):
//   A (256 rows x 32 k) at +0, B at +8192. 8-elem segment s of row r stored at
//   s ^ ((r>>1)&3) (2-way aliasing = free; measured 0 conflicts). Staged via
//   global_load_lds with pre-swizzled global source (linear LDS dest).
// Schedule per K-tile t (cur=t&3): 2 phases (mh = M-half of compute):
//   {4|8 ds_read_b128 ; stage unit mh of tile t+3 into buf[(t+3)&3] ;
//    s_barrier ; setprio(1) ; 16 MFMA ; setprio(0) ; [vmcnt(8) phase 1] ; s_barrier}
// Per-wave loads: 2/phase, 4/tile. Steady state: end-of-tile outstanding =
// 4(t+1)+4(t+2)+4(t+3)=12; vmcnt(8) drains exactly tile t+1's loads -> the
// trailing barrier publishes buf[(t+1)&3]. Prefetch distance ~5 phases (~800+cy)
// covers HBM latency. Epilogue tiles 63/64/65 drain 8 -> 4 -> 0.
// Buffer-free proof: tile t writes buf[(t+3)&3] = buf[(t-1)&3]; all waves'
// ds_reads of tile t-1 complete before its final barrier (lgkm waits precede
// the MFMAs), and tile t's stage issues only after that barrier.
__global__ __launch_bounds__(512, 2) void gemm256_bt(const u16* __restrict__ A,
                                                     const u16* __restrict__ Bt,
                                                     u16* __restrict__ C) {
  __shared__ u16 sh[4 * 16384];
  const int cpx = gridDim.x >> 3;  // gridDim.x % 8 == 0
  const int swz = (blockIdx.x & 7) * cpx + (blockIdx.x >> 3);
  const int bm = swz & 15;   // M/256 = 16 fixed
  const int bn = swz >> 4;
  const int tid = threadIdx.x;
  const int w = tid >> 6, lane = tid & 63;
  const int quad = lane >> 4, l15 = lane & 15;
  const int wm = w >> 2, wn = w & 3;  // 2M x 4N waves
  const int rseg = (quad ^ ((l15 >> 1) & 3)) * 8;
  const int aoff = (wm * 128 + l15) * 32 + rseg;
  const int boff = (wn * 64 + l15) * 32 + rseg;
  const int srow = lane >> 2;
  const int sseg = ((lane & 3) ^ ((lane >> 3) & 3)) * 8;
  const u16* aSrc = A + (long)(bm * 256 + w * 16 + srow) * 2112 + sseg;
  const u16* bSrc = Bt + (long)(bn * 256 + w * 16 + srow) * 2112 + sseg;

  f32x4 acc[8][4];
#pragma unroll
  for (int i = 0; i < 8; i++)
#pragma unroll
    for (int j = 0; j < 4; j++) acc[i][j] = {0.f, 0.f, 0.f, 0.f};

  // prologue: stage tiles 0,1,2 into bufs 0,1,2 (per tile: A-mh0,B-mh0,A-mh1,B-mh1)
#pragma unroll
  for (int t = 0; t < 3; t++) {
    gl_lds16(aSrc + t * 32, sh + t * 16384 + w * 512);
    gl_lds16(bSrc + t * 32, sh + t * 16384 + 8192 + w * 512);
    gl_lds16(aSrc + 128L * 2112 + t * 32, sh + t * 16384 + 4096 + w * 512);
    gl_lds16(bSrc + 128L * 2112 + t * 32, sh + t * 16384 + 8192 + 4096 + w * 512);
  }
  asm volatile("s_waitcnt vmcnt(8)" ::: "memory");
  __builtin_amdgcn_s_barrier();

  s8v bf[4];
  int kcol = 96;  // staging column: tile t stages tile t+3 at col (t+3)*32

#define STAGE_UNIT(NB, MH)                                                    \
  gl_lds16(aSrc + (MH) * (128L * 2112) + kcol,                                \
           sh + (NB) * 16384 + (MH) * 4096 + w * 512);                        \
  gl_lds16(bSrc + (MH) * (128L * 2112) + kcol,                                \
           sh + (NB) * 16384 + 8192 + (MH) * 4096 + w * 512);

#define PHASE(CUR, MH, DOB, STG, VM)                                          \
  {                                                                           \
    const u16* Ab = sh + (CUR) * 16384 + aoff + (MH) * 2048;                  \
    s8v af0 = *(const s8v*)(Ab);                                              \
    s8v af1 = *(const s8v*)(Ab + 512);                                        \
    s8v af2 = *(const s8v*)(Ab + 1024);                                       \
    s8v af3 = *(const s8v*)(Ab + 1536);                                       \
    if (DOB) {                                                                \
      const u16* Bb = sh + (CUR) * 16384 + 8192 + boff;                       \
      bf[0] = *(const s8v*)(Bb);                                              \
      bf[1] = *(const s8v*)(Bb + 512);                                        \
      bf[2] = *(const s8v*)(Bb + 1024);                                       \
      bf[3] = *(const s8v*)(Bb + 1536);                                       \
    }                                                                         \
    if (STG) { STAGE_UNIT((((CUR) + 3) & 3), MH) }                            \
    __builtin_amdgcn_s_barrier();                                             \
    __builtin_amdgcn_s_setprio(1);                                            \
    _Pragma("unroll") for (int ni = 0; ni < 4; ni++) {                        \
      acc[(MH) * 4 + 0][ni] = mfma16(af0, bf[ni], acc[(MH) * 4 + 0][ni]);     \
      acc[(MH) * 4 + 1][ni] = mfma16(af1, bf[ni], acc[(MH) * 4 + 1][ni]);     \
      acc[(MH) * 4 + 2][ni] = mfma16(af2, bf[ni], acc[(MH) * 4 + 2][ni]);     \
      acc[(MH) * 4 + 3][ni] = mfma16(af3, bf[ni], acc[(MH) * 4 + 3][ni]);     \
    }                                                                         \
    __builtin_amdgcn_s_setprio(0);                                            \
    if ((VM) == 8) asm volatile("s_waitcnt vmcnt(8)" ::: "memory");           \
    if ((VM) == 4) asm volatile("s_waitcnt vmcnt(4)" ::: "memory");           \
    if ((VM) == 0) asm volatile("s_waitcnt vmcnt(0)" ::: "memory");           \
    __builtin_amdgcn_s_barrier();                                             \
  }

#define TILE(CUR, STG, VM)       \
  PHASE(CUR, 0, 1, STG, -1)      \
  PHASE(CUR, 1, 0, STG, VM)      \
  kcol += 32;

  for (int t4 = 0; t4 < 15; t4++) {  // tiles 0..59
    TILE(0, 1, 8)
    TILE(1, 1, 8)
    TILE(2, 1, 8)
    TILE(3, 1, 8)
  }
  TILE(0, 1, 8)   // tile 60 (stages 63)
  TILE(1, 1, 8)   // tile 61 (stages 64)
  TILE(2, 1, 8)   // tile 62 (stages 65)
  TILE(3, 0, 4)   // tile 63 (outstanding 8 -> drain t64's 4)
  TILE(0, 0, 0)   // tile 64 (outstanding 4 -> drain t65's 4)
  TILE(1, 0, -1)  // tile 65

#undef TILE
#undef PHASE
#undef STAGE_UNIT

  const long m0 = (long)bm * 256 + wm * 128;
  const long n0 = (long)bn * 256 + wn * 64;
#pragma unroll
  for (int mi = 0; mi < 8; mi++)
#pragma unroll
    for (int r = 0; r < 4; r++) {
      long row = m0 + mi * 16 + quad * 4 + r;
#pragma unroll
      for (int ni = 0; ni < 4; ni++) {
        long col = n0 + ni * 16 + l15;
        C[row * 18688 + col] = f2bf(acc[mi][ni][r]);
      }
    }
}

// ---------------- causal flash attention (MQA): K from proj, V from v_t (pre-transposed)
__global__ __launch_bounds__(256) void flash_k(const u16* __restrict__ proj,
                                               const u16* __restrict__ v_t,
                                               u16* __restrict__ ctx) {
  __shared__ u16 Kt[4 * 1024];
  __shared__ u16 Vx[8 * 512];
  __shared__ u16 Pw[4 * 512];
  const int qt = blockIdx.x, h = blockIdx.y, b = blockIdx.z;
  const int tid = threadIdx.x;
  const int w = tid >> 6, lane = tid & 63, quad = lane >> 4, l15 = lane & 15;
  const int qbase = qt * 64 + w * 16;

  s8v qf[4];
  {
    long rowQ = (long)b * 2048 + qbase + l15;
    const u16* qp = proj + rowQ * 18688 + h * 128 + quad * 8;
#pragma unroll
    for (int kk = 0; kk < 4; kk++) qf[kk] = *(const s8v*)(qp + kk * 32);
  }
  f32x4 o[8];
#pragma unroll
  for (int i = 0; i < 8; i++) o[i] = {0.f, 0.f, 0.f, 0.f};
  float m_i[4] = {-1e30f, -1e30f, -1e30f, -1e30f};
  float l_i[4] = {0.f, 0.f, 0.f, 0.f};

  const int srow = lane >> 2;
  const int sseg = ((lane & 3) ^ ((lane >> 3) & 3)) * 8;
  const int rseg = (quad ^ ((l15 >> 1) & 3)) * 8;

  const int nkb = 2 * qt + 2;
  for (int kb = 0; kb < nkb; kb++) {
    const int k0 = kb * 32;
    {
      long rK = (long)b * 2048 + k0;
#pragma unroll
      for (int h2 = 0; h2 < 2; h2++)
        gl_lds16(proj + (rK + h2 * 16 + srow) * 18688 + 2048 + w * 32 + sseg,
                 Kt + w * 1024 + h2 * 512);
#pragma unroll
      for (int h2 = 0; h2 < 2; h2++)
        gl_lds16(v_t + ((long)b * 128 + w * 32 + h2 * 16 + srow) * 2048 + k0 + sseg,
                 Vx + (w * 2 + h2) * 512);
    }
    __syncthreads();
    if (k0 <= qbase + 15) {
      f32x4 s[2];
#pragma unroll
      for (int ni = 0; ni < 2; ni++) {
        f32x4 a = {0.f, 0.f, 0.f, 0.f};
#pragma unroll
        for (int kk = 0; kk < 4; kk++) {
          s8v kf = *(const s8v*)(Kt + kk * 1024 + (ni * 16 + l15) * 32 + rseg);
          a = mfma16(qf[kk], kf, a);
        }
        s[ni] = a;
      }
#pragma unroll
      for (int ni = 0; ni < 2; ni++) {
        int kg = k0 + ni * 16 + l15;
#pragma unroll
        for (int r = 0; r < 4; r++)
          if (kg > qbase + quad * 4 + r) s[ni][r] = -1e30f;
      }
      float al[4];
#pragma unroll
      for (int r = 0; r < 4; r++) {
        float mx = fmaxf(s[0][r], s[1][r]);
#pragma unroll
        for (int off = 8; off > 0; off >>= 1)
          mx = fmaxf(mx, __shfl_xor(mx, off, 16));
        float mn = fmaxf(m_i[r], mx);
        al[r] = __expf(m_i[r] - mn);
        m_i[r] = mn;
      }
#pragma unroll
      for (int ni = 0; ni < 2; ni++)
#pragma unroll
        for (int r = 0; r < 4; r++) s[ni][r] = __expf(s[ni][r] - m_i[r]);
#pragma unroll
      for (int r = 0; r < 4; r++) {
        float rs = s[0][r] + s[1][r];
#pragma unroll
        for (int off = 8; off > 0; off >>= 1)
          rs += __shfl_xor(rs, off, 16);
        l_i[r] = l_i[r] * al[r] + rs;
      }
#pragma unroll
      for (int ni = 0; ni < 2; ni++)
#pragma unroll
        for (int r = 0; r < 4; r++) {
          int p = quad * 4 + r;
          int sg = ni * 2 + (l15 >> 3);
          int sp = sg ^ ((p >> 1) & 3);
          Pw[w * 512 + p * 32 + sp * 8 + (l15 & 7)] = f2bf(s[ni][r]);
        }
      __asm__ volatile("s_waitcnt lgkmcnt(0)" ::: "memory");
#pragma unroll
      for (int nt = 0; nt < 8; nt++)
#pragma unroll
        for (int r = 0; r < 4; r++) o[nt][r] *= al[r];
      s8v pf = *(const s8v*)(Pw + w * 512 + l15 * 32 + rseg);
#pragma unroll
      for (int nt = 0; nt < 8; nt++) {
        s8v vf = *(const s8v*)(Vx + (nt * 16 + l15) * 32 + rseg);
        o[nt] = mfma16(pf, vf, o[nt]);
      }
    }
    __syncthreads();
  }
  float inv[4];
#pragma unroll
  for (int r = 0; r < 4; r++) inv[r] = 1.f / l_i[r];
#pragma unroll
  for (int nt = 0; nt < 8; nt++)
#pragma unroll
    for (int r = 0; r < 4; r++) {
      long row = (long)b * 2048 + qbase + quad * 4 + r;
      ctx[row * 2080 + h * 128 + nt * 16 + l15] = f2bf(o[nt][r] * inv[r]);
    }
}

// ---------------- workspace layout (bytes)
// wf_t is dead after the big GEMM -> its region is reused for ctx_aug.
#define OFF_WF   0L                       // wf_t 18688x2112 bf16 = 78,938,112 ; later ctx_aug (17,039,360)
#define OFF_WO   78938112L                // wo_t 2048x2080 bf16  =  8,519,680
#define OFF_WFF  87457792L                // wff_t 2048x8192 bf16 = 33,554,432
#define OFF_XN   121012224L               // xn_aug 4096x2112 bf16 = 17,301,504 (reused as v_t)
#define OFF_PROJ 138313728L               // proj 4096x18688 bf16 = 153,092,096
#define WS_NEED  291405824L

extern "C" void kernel_launch(void* const* d_in, const int* in_sizes, int n_in,
                              void* d_out, int out_size, void* d_ws, size_t ws_size,
                              hipStream_t stream) {
  const float* x       = (const float*)d_in[0];
  const float* gamma   = (const float*)d_in[1];
  const float* w_fused = (const float*)d_in[2];
  const float* w_attn  = (const float*)d_in[3];
  const float* w_ff    = (const float*)d_in[4];
  const float* a_q = (const float*)d_in[5];
  const float* b_q = (const float*)d_in[6];
  const float* a_k = (const float*)d_in[7];
  const float* b_k = (const float*)d_in[8];
  const float* a_v = (const float*)d_in[9];
  const float* b_v = (const float*)d_in[10];
  const float* a_o = (const float*)d_in[11];
  const float* b_o = (const float*)d_in[12];
  float* out = (float*)d_out;
  if (ws_size < (size_t)WS_NEED) return;

  char* ws = (char*)d_ws;
  u16* wf_t    = (u16*)(ws + OFF_WF);
  u16* ctx_aug = (u16*)(ws + OFF_WF);  // reuses wf_t region after big GEMM
  u16* wo_t    = (u16*)(ws + OFF_WO);
  u16* wff_t   = (u16*)(ws + OFF_WFF);
  u16* xn_aug  = (u16*)(ws + OFF_XN);
  u16* v_t     = (u16*)(ws + OFF_XN);  // reuses xn_aug region after big GEMM
  u16* proj    = (u16*)(ws + OFF_PROJ);

  dim3 tb(32, 8);
  transpose_cvt<<<dim3(18688 / 32, 2048 / 32), tb, 0, stream>>>(w_fused, wf_t, 2048, 18688, 2112);
  transpose_cvt<<<dim3(2048 / 32, 2048 / 32), tb, 0, stream>>>(w_attn, wo_t, 2048, 2048, 2080);
  transpose_cvt<<<dim3(2048 / 32, 8192 / 32), tb, 0, stream>>>(w_ff, wff_t, 8192, 2048, 8192);
  fill_aug_k<<<(18688 * 64 + 255) / 256, 256, 0, stream>>>(wf_t, 18688, 2112, 64, b_q, b_k, b_v);
  fill_aug_k<<<(2048 * 32 + 255) / 256, 256, 0, stream>>>(wo_t, 2048, 2080, 32, b_o, nullptr, nullptr);

  layernorm_k<<<4096, 256, 0, stream>>>(x, gamma, xn_aug);
  lora_down_x<<<4096, 256, 0, stream>>>(xn_aug, a_q, a_k, a_v);

  // proj = xn_aug @ wf_t^T  (q|k|v|x1|gate with QKV-LoRA folded into K-aug, K padded to 2112)
  gemm256_bt<<<dim3(16 * (18688 / 256)), 512, 0, stream>>>(xn_aug, wf_t, proj);

  rope_k<<<(4096 * 17 * 64) / 256, 256, 0, stream>>>(proj);
  silu_mul_k<<<(4096 * 1024) / 256, 256, 0, stream>>>(proj);
  vtrans<<<dim3(64, 4, 2), tb, 0, stream>>>(proj, v_t);

  flash_k<<<dim3(32, 16, 2), 256, 0, stream>>>(proj, v_t, ctx_aug);
  lora_down_ctx<<<4096, 256, 0, stream>>>(ctx_aug, a_o);

  // d_out = ctx_aug @ wo_t^T (o-LoRA folded), then += h @ wff_t^T
  gemm_bt<STORE_F32><<<dim3(256, 2), 256, 0, stream>>>(
      ctx_aug, 2080, wo_t, 2080, out, 2048, 2080, 16);
  gemm_bt<ADD_F32><<<dim3(256, 2), 256, 0, stream>>>(
      proj + 2304, 18688, wff_t, 8192, out, 2048, 8192, 16);
}

// Round 4
// 1314.860 us; speedup vs baseline: 1.1045x; 1.0436x over previous
//
#include <hip/hip_runtime.h>

typedef unsigned short u16;
typedef __attribute__((ext_vector_type(8))) short s8v;
typedef __attribute__((ext_vector_type(4))) short s4v;
typedef __attribute__((ext_vector_type(4))) float f32x4;

__device__ __forceinline__ u16 f2bf(float f) {
  unsigned int u = __float_as_uint(f);
  u += ((u >> 16) & 1u) + 0x7FFFu;
  return (u16)(u >> 16);
}
__device__ __forceinline__ float bf2f(u16 h) {
  return __uint_as_float(((unsigned int)h) << 16);
}
__device__ __forceinline__ void gl_lds16(const void* g, void* l) {
  __builtin_amdgcn_global_load_lds(
      (__attribute__((address_space(1))) void*)g,
      (__attribute__((address_space(3))) void*)l, 16, 0, 0);
}
__device__ __forceinline__ f32x4 mfma16(s8v a, s8v b, f32x4 c) {
  return __builtin_amdgcn_mfma_f32_16x16x32_bf16(a, b, c, 0, 0, 0);
}

// ---------------- transpose + fp32->bf16 convert: out[c][r] = bf16(in[r][c])
__global__ void transpose_cvt(const float* __restrict__ in, u16* __restrict__ out,
                              int rows, int cols, int ldo) {
  __shared__ float tile[32][33];
  int c0 = blockIdx.x * 32, r0 = blockIdx.y * 32;
  int tx = threadIdx.x, ty = threadIdx.y;  // 32 x 8
#pragma unroll
  for (int i = 0; i < 4; i++)
    tile[ty + i * 8][tx] = in[(long)(r0 + ty + i * 8) * cols + c0 + tx];
  __syncthreads();
#pragma unroll
  for (int i = 0; i < 4; i++)
    out[(long)(c0 + ty + i * 8) * ldo + r0 + tx] = f2bf(tile[tx][ty + i * 8]);
}

// ---------------- V transpose: v_t[b][d][n] = proj[b,n][2176+d] (bf16)
__global__ void vtrans(const u16* __restrict__ proj, u16* __restrict__ v_t) {
  __shared__ u16 tile[32][33];
  int n0 = blockIdx.x * 32, d0 = blockIdx.y * 32, b = blockIdx.z;
  int tx = threadIdx.x, ty = threadIdx.y;  // 32 x 8
#pragma unroll
  for (int i = 0; i < 4; i++)
    tile[ty + i * 8][tx] =
        proj[((long)b * 2048 + n0 + ty + i * 8) * 18688 + 2176 + d0 + tx];
  __syncthreads();
#pragma unroll
  for (int i = 0; i < 4; i++)
    v_t[((long)b * 128 + d0 + ty + i * 8) * 2048 + n0 + tx] = tile[tx][ty + i * 8];
}

// ---------------- fill aug K-cols [2048,2048+naug) of a transposed weight
__global__ void fill_aug_k(u16* __restrict__ wt, int N, int ldo, int naug,
                           const float* __restrict__ bq, const float* __restrict__ bk,
                           const float* __restrict__ bv) {
  long idx = (long)blockIdx.x * 256 + threadIdx.x;
  if (idx >= (long)N * naug) return;
  int n = (int)(idx / naug), j = (int)(idx % naug);
  float v = 0.f;
  if (bq && j < 8 && n < 2048) v = bq[j * 2048 + n];
  else if (bk && j >= 8 && j < 16 && n >= 2048 && n < 2176) v = bk[(j - 8) * 128 + (n - 2048)];
  else if (bv && j >= 16 && j < 24 && n >= 2176 && n < 2304) v = bv[(j - 16) * 128 + (n - 2176)];
  wt[(long)n * ldo + 2048 + j] = f2bf(v);
}

// ---------------- layernorm: x fp32 (4096x2048) -> xn_aug bf16 cols [0,2048), ld 2112
__global__ __launch_bounds__(256) void layernorm_k(const float* __restrict__ x,
                                                   const float* __restrict__ gamma,
                                                   u16* __restrict__ xn) {
  const int row = blockIdx.x, tid = threadIdx.x;
  const float* xr = x + (long)row * 2048 + tid * 8;
  float4 v0 = *(const float4*)xr;
  float4 v1 = *(const float4*)(xr + 4);
  float vals[8] = {v0.x, v0.y, v0.z, v0.w, v1.x, v1.y, v1.z, v1.w};
  float s = 0.f, q = 0.f;
#pragma unroll
  for (int e = 0; e < 8; e++) { s += vals[e]; q += vals[e] * vals[e]; }
#pragma unroll
  for (int off = 32; off > 0; off >>= 1) {
    s += __shfl_down(s, off, 64);
    q += __shfl_down(q, off, 64);
  }
  __shared__ float red[8];
  const int w = tid >> 6, lane = tid & 63;
  if (lane == 0) { red[w] = s; red[4 + w] = q; }
  __syncthreads();
  if (tid == 0) {
    float S = red[0] + red[1] + red[2] + red[3];
    float Q = red[4] + red[5] + red[6] + red[7];
    float mu = S * (1.f / 2048.f);
    float var = Q * (1.f / 2048.f) - mu * mu;
    red[0] = mu; red[1] = rsqrtf(var + 1e-5f);
  }
  __syncthreads();
  float mu = red[0], rs = red[1];
  const float* g = gamma + tid * 8;
  u16 ov[8];
#pragma unroll
  for (int e = 0; e < 8; e++) ov[e] = f2bf((vals[e] - mu) * rs * g[e]);
  *(s8v*)(xn + (long)row * 2112 + tid * 8) = *(const s8v*)ov;
}

// ---------------- t_q|t_k|t_v = xn @ a_* -> bf16 into xn_aug cols [2048,2080); zero [2080,2112)
__global__ __launch_bounds__(256) void lora_down_x(u16* __restrict__ xn_aug,
                                                   const float* __restrict__ aq,
                                                   const float* __restrict__ ak,
                                                   const float* __restrict__ av) {
  const int row = blockIdx.x, tid = threadIdx.x;
  s8v xv = *(const s8v*)(xn_aug + (long)row * 2112 + tid * 8);
  float acc[3][8];
#pragma unroll
  for (int m = 0; m < 3; m++)
#pragma unroll
    for (int j = 0; j < 8; j++) acc[m][j] = 0.f;
  const float* mats[3] = {aq, ak, av};
#pragma unroll
  for (int e = 0; e < 8; e++) {
    float xe = bf2f((u16)xv[e]);
    int k = tid * 8 + e;
#pragma unroll
    for (int m = 0; m < 3; m++) {
      const float4* ap = (const float4*)(mats[m] + (long)k * 8);
      float4 a0 = ap[0], a1 = ap[1];
      acc[m][0] += xe * a0.x; acc[m][1] += xe * a0.y;
      acc[m][2] += xe * a0.z; acc[m][3] += xe * a0.w;
      acc[m][4] += xe * a1.x; acc[m][5] += xe * a1.y;
      acc[m][6] += xe * a1.z; acc[m][7] += xe * a1.w;
    }
  }
#pragma unroll
  for (int m = 0; m < 3; m++)
#pragma unroll
    for (int j = 0; j < 8; j++)
#pragma unroll
      for (int off = 32; off > 0; off >>= 1)
        acc[m][j] += __shfl_down(acc[m][j], off, 64);
  __shared__ float red[4][24];
  const int w = tid >> 6, lane = tid & 63;
  if (lane == 0)
    for (int m = 0; m < 3; m++)
      for (int j = 0; j < 8; j++) red[w][m * 8 + j] = acc[m][j];
  __syncthreads();
  if (tid < 64) {
    float v = 0.f;
    if (tid < 24) v = red[0][tid] + red[1][tid] + red[2][tid] + red[3][tid];
    xn_aug[(long)row * 2112 + 2048 + tid] = f2bf(v);
  }
}

// ---------------- t_o = ctx @ a_o -> bf16 into ctx_aug cols [2048,2080)
__global__ __launch_bounds__(256) void lora_down_ctx(u16* __restrict__ ctx_aug,
                                                     const float* __restrict__ ao) {
  const int row = blockIdx.x, tid = threadIdx.x;
  s8v xv = *(const s8v*)(ctx_aug + (long)row * 2080 + tid * 8);
  float acc[8];
#pragma unroll
  for (int j = 0; j < 8; j++) acc[j] = 0.f;
#pragma unroll
  for (int e = 0; e < 8; e++) {
    float xe = bf2f((u16)xv[e]);
    int k = tid * 8 + e;
    const float4* ap = (const float4*)(ao + (long)k * 8);
    float4 a0 = ap[0], a1 = ap[1];
    acc[0] += xe * a0.x; acc[1] += xe * a0.y; acc[2] += xe * a0.z; acc[3] += xe * a0.w;
    acc[4] += xe * a1.x; acc[5] += xe * a1.y; acc[6] += xe * a1.z; acc[7] += xe * a1.w;
  }
#pragma unroll
  for (int j = 0; j < 8; j++)
#pragma unroll
    for (int off = 32; off > 0; off >>= 1)
      acc[j] += __shfl_down(acc[j], off, 64);
  __shared__ float red[4][8];
  const int w = tid >> 6, lane = tid & 63;
  if (lane == 0)
    for (int j = 0; j < 8; j++) red[w][j] = acc[j];
  __syncthreads();
  if (tid < 32) {
    float v = 0.f;
    if (tid < 8) v = red[0][tid] + red[1][tid] + red[2][tid] + red[3][tid];
    ctx_aug[(long)row * 2080 + 2048 + tid] = f2bf(v);
  }
}

// ---------------- RoPE (+ q scale) in-place on proj cols [0,2048) (q) and [2048,2176) (k)
__global__ void rope_k(u16* __restrict__ proj) {
  int idx = blockIdx.x * 256 + threadIdx.x;  // 4096*17*64
  int i = idx & 63;
  int u = (idx >> 6) % 17;
  int row = idx / (17 * 64);
  int n = row & 2047;
  float invf = __powf(10000.f, -(float)i * (1.f / 64.f));
  float ang = (float)n * invf;
  float cs = cosf(ang), sn = sinf(ang);
  int cb = (u < 16) ? u * 128 : 2048;
  u16* p = proj + (long)row * 18688 + cb + i;
  float t1 = bf2f(p[0]), t2 = bf2f(p[64]);
  float sc = (u < 16) ? 0.08838834764831845f : 1.f;  // 128^-0.5 on q only
  p[0]  = f2bf((t1 * cs - t2 * sn) * sc);
  p[64] = f2bf((t2 * cs + t1 * sn) * sc);
}

// ---------------- h = silu(gate)*x1, in-place into x1 region of proj
__global__ void silu_mul_k(u16* __restrict__ proj) {
  long idx = (long)blockIdx.x * 256 + threadIdx.x;  // 4096*1024
  int row = (int)(idx >> 10);
  int c8 = (int)(idx & 1023) * 8;
  u16* px = proj + (long)row * 18688 + 2304 + c8;
  const u16* pg = proj + (long)row * 18688 + 10496 + c8;
  s8v xv = *(const s8v*)px;
  s8v gv = *(const s8v*)pg;
  u16 ov[8];
#pragma unroll
  for (int e = 0; e < 8; e++) {
    float x1 = bf2f((u16)xv[e]);
    float g = bf2f((u16)gv[e]);
    ov[e] = f2bf(x1 * g / (1.f + __expf(-g)));
  }
  *(s8v*)px = *(const s8v*)ov;
}

// ================= 256x256 deep-pipelined GEMM, big projection.
// C(4096 x 18688) = A(4096 x 2112, ld 2112) @ Bt(18688 x 2112, ld 2112)^T, C bf16 ld 18688.
// K = 2112 -> 66 K-tiles of 32. Grid = 16*73 = 1168 (1D), 512 threads.
// LDS: 4-deep ring of 32KB buffers. Row-seg XOR swizzle (2-way aliasing, free).
// ONE barrier per K-tile (after the per-wave vmcnt). Proof:
//   publish: buf[t+1] valid after tile t's barrier (vmcnt(8) drained its loads
//   in EVERY wave, then barrier). anti-hazard: stage at tile t overwrites
//   buf[(t-1)&3]; every wave's ds_reads of tile t-1 completed before its own
//   lgkm-waited MFMAs, hence before tile t-1's barrier, which all waves passed
//   before any wave issues tile t's stage. Removing the per-phase barriers
//   lets waves de-sync within a tile -> ds_read of one wave overlaps MFMA of
//   another (wave-level overlap the lockstep forbade).
// MFMA operands SWAPPED (bf,af): lane holds 4 consecutive N-cols -> 8B C-stores.
__global__ __launch_bounds__(512, 2) void gemm256_bt(const u16* __restrict__ A,
                                                     const u16* __restrict__ Bt,
                                                     u16* __restrict__ C) {
  __shared__ u16 sh[4 * 16384];
  const int cpx = gridDim.x >> 3;  // gridDim.x % 8 == 0
  const int swz = (blockIdx.x & 7) * cpx + (blockIdx.x >> 3);
  const int bm = swz & 15;   // M/256 = 16 fixed
  const int bn = swz >> 4;
  const int tid = threadIdx.x;
  const int w = tid >> 6, lane = tid & 63;
  const int quad = lane >> 4, l15 = lane & 15;
  const int wm = w >> 2, wn = w & 3;  // 2M x 4N waves
  const int rseg = (quad ^ ((l15 >> 1) & 3)) * 8;
  const int aoff = (wm * 128 + l15) * 32 + rseg;
  const int boff = (wn * 64 + l15) * 32 + rseg;
  const int srow = lane >> 2;
  const int sseg = ((lane & 3) ^ ((lane >> 3) & 3)) * 8;
  const u16* aSrc = A + (long)(bm * 256 + w * 16 + srow) * 2112 + sseg;
  const u16* bSrc = Bt + (long)(bn * 256 + w * 16 + srow) * 2112 + sseg;

  f32x4 acc[8][4];
#pragma unroll
  for (int i = 0; i < 8; i++)
#pragma unroll
    for (int j = 0; j < 4; j++) acc[i][j] = {0.f, 0.f, 0.f, 0.f};

  // prologue: stage tiles 0,1,2 into bufs 0,1,2
#pragma unroll
  for (int t = 0; t < 3; t++) {
    gl_lds16(aSrc + t * 32, sh + t * 16384 + w * 512);
    gl_lds16(bSrc + t * 32, sh + t * 16384 + 8192 + w * 512);
    gl_lds16(aSrc + 128L * 2112 + t * 32, sh + t * 16384 + 4096 + w * 512);
    gl_lds16(bSrc + 128L * 2112 + t * 32, sh + t * 16384 + 8192 + 4096 + w * 512);
  }
  asm volatile("s_waitcnt vmcnt(8)" ::: "memory");
  __builtin_amdgcn_s_barrier();

  s8v bf[4];
  int kcol = 96;  // staging column: tile t stages tile t+3 at col (t+3)*32

#define STAGE_UNIT(NB, MH)                                                    \
  gl_lds16(aSrc + (MH) * (128L * 2112) + kcol,                                \
           sh + (NB) * 16384 + (MH) * 4096 + w * 512);                        \
  gl_lds16(bSrc + (MH) * (128L * 2112) + kcol,                                \
           sh + (NB) * 16384 + 8192 + (MH) * 4096 + w * 512);

#define PHASE(CUR, MH, DOB, STG, VM)                                          \
  {                                                                           \
    const u16* Ab = sh + (CUR) * 16384 + aoff + (MH) * 2048;                  \
    s8v af0 = *(const s8v*)(Ab);                                              \
    s8v af1 = *(const s8v*)(Ab + 512);                                        \
    s8v af2 = *(const s8v*)(Ab + 1024);                                       \
    s8v af3 = *(const s8v*)(Ab + 1536);                                       \
    if (DOB) {                                                                \
      const u16* Bb = sh + (CUR) * 16384 + 8192 + boff;                       \
      bf[0] = *(const s8v*)(Bb);                                              \
      bf[1] = *(const s8v*)(Bb + 512);                                        \
      bf[2] = *(const s8v*)(Bb + 1024);                                       \
      bf[3] = *(const s8v*)(Bb + 1536);                                       \
    }                                                                         \
    if (STG) { STAGE_UNIT((((CUR) + 3) & 3), MH) }                            \
    __builtin_amdgcn_s_setprio(1);                                            \
    _Pragma("unroll") for (int ni = 0; ni < 4; ni++) {                        \
      acc[(MH) * 4 + 0][ni] = mfma16(bf[ni], af0, acc[(MH) * 4 + 0][ni]);     \
      acc[(MH) * 4 + 1][ni] = mfma16(bf[ni], af1, acc[(MH) * 4 + 1][ni]);     \
      acc[(MH) * 4 + 2][ni] = mfma16(bf[ni], af2, acc[(MH) * 4 + 2][ni]);     \
      acc[(MH) * 4 + 3][ni] = mfma16(bf[ni], af3, acc[(MH) * 4 + 3][ni]);     \
    }                                                                         \
    __builtin_amdgcn_s_setprio(0);                                            \
    if ((VM) == 8) asm volatile("s_waitcnt vmcnt(8)" ::: "memory");           \
    if ((VM) == 4) asm volatile("s_waitcnt vmcnt(4)" ::: "memory");           \
    if ((VM) == 0) asm volatile("s_waitcnt vmcnt(0)" ::: "memory");           \
    if ((VM) != -1) __builtin_amdgcn_s_barrier();                             \
  }

#define TILE(CUR, STG, VM)       \
  PHASE(CUR, 0, 1, STG, -1)      \
  PHASE(CUR, 1, 0, STG, VM)      \
  kcol += 32;

  for (int t4 = 0; t4 < 15; t4++) {  // tiles 0..59
    TILE(0, 1, 8)
    TILE(1, 1, 8)
    TILE(2, 1, 8)
    TILE(3, 1, 8)
  }
  TILE(0, 1, 8)   // tile 60 (stages 63)
  TILE(1, 1, 8)   // tile 61 (stages 64)
  TILE(2, 1, 8)   // tile 62 (stages 65)
  TILE(3, 0, 4)   // tile 63 (outstanding 8 -> drain t64's 4)
  TILE(0, 0, 0)   // tile 64 (outstanding 4 -> drain t65's 4)
  TILE(1, 0, -1)  // tile 65

#undef TILE
#undef PHASE
#undef STAGE_UNIT

  // transposed-acc store: lane holds 4 consecutive N-cols per (mi,ni) -> 8B stores
  const long m0 = (long)bm * 256 + wm * 128;
  const long n0 = (long)bn * 256 + wn * 64;
#pragma unroll
  for (int mi = 0; mi < 8; mi++) {
    long row = m0 + mi * 16 + l15;
#pragma unroll
    for (int ni = 0; ni < 4; ni++) {
      long col = n0 + ni * 16 + quad * 4;
      s4v pk = {(short)f2bf(acc[mi][ni][0]), (short)f2bf(acc[mi][ni][1]),
                (short)f2bf(acc[mi][ni][2]), (short)f2bf(acc[mi][ni][3])};
      *(s4v*)(C + row * 18688 + col) = pk;
    }
  }
}

// ================= 128x256 deep-pipelined output GEMM (f32 out).
// C(4096 x 2048 f32) = A(4096 x K bf16) @ Bt(2048 x K bf16)^T. Grid 256 = 32M x 8N
// blocks = exactly 1 round on 256 CUs (no tail). 512 thr, 8 waves 2Mx4N, 64x64/wave.
// LDS: 4-ring of 24KB buffers (A 8KB + B 16KB) = 96KB. Same swizzle/stage pattern
// as gemm256_bt. 3 gl_lds/wave/tile; vmcnt(6) steady (tiles t+2,t+3 in flight);
// one barrier per tile. Transposed MFMA -> float4 stores (ADD = vector RMW).
enum { STORE_F32 = 1, ADD_F32 = 2 };
template <int MODE>
__global__ __launch_bounds__(512, 1) void gemm_out(const u16* __restrict__ A, int lda,
                                                   const u16* __restrict__ Bt, int ldb,
                                                   float* __restrict__ Cv, int ldc, int K) {
  __shared__ u16 sh[4 * 12288];
  const int cpx = gridDim.x >> 3;
  const int swz = (blockIdx.x & 7) * cpx + (blockIdx.x >> 3);
  const int bm = swz & 31;   // 32 M-blocks of 128
  const int bn = swz >> 5;   // 8 N-blocks of 256
  const int tid = threadIdx.x;
  const int w = tid >> 6, lane = tid & 63;
  const int quad = lane >> 4, l15 = lane & 15;
  const int wm = w >> 2, wn = w & 3;  // per-wave 64x64
  const int rseg = (quad ^ ((l15 >> 1) & 3)) * 8;
  const int aoff = (wm * 64 + l15) * 32 + rseg;
  const int boff = 4096 + (wn * 64 + l15) * 32 + rseg;
  const int srow = lane >> 2;
  const int sseg = ((lane & 3) ^ ((lane >> 3) & 3)) * 8;
  const u16* aSrc = A + (long)(bm * 128 + w * 16 + srow) * lda + sseg;
  const u16* bSrc0 = Bt + (long)(bn * 256 + w * 16 + srow) * ldb + sseg;
  const u16* bSrc1 = Bt + (long)(bn * 256 + 128 + w * 16 + srow) * ldb + sseg;
  const int NT = K >> 5;

  f32x4 acc[4][4];
#pragma unroll
  for (int i = 0; i < 4; i++)
#pragma unroll
    for (int j = 0; j < 4; j++) acc[i][j] = {0.f, 0.f, 0.f, 0.f};

  // prologue: stage tiles 0,1,2
#pragma unroll
  for (int t = 0; t < 3; t++) {
    gl_lds16(aSrc + t * 32, sh + t * 12288 + w * 512);
    gl_lds16(bSrc0 + t * 32, sh + t * 12288 + 4096 + w * 512);
    gl_lds16(bSrc1 + t * 32, sh + t * 12288 + 8192 + w * 512);
  }
  asm volatile("s_waitcnt vmcnt(6)" ::: "memory");
  __builtin_amdgcn_s_barrier();

  int kcol = 96;
  for (int t = 0; t < NT; ++t) {
    const int cur = (t & 3) * 12288;
    const u16* Ab = sh + cur + aoff;
    const u16* Bb = sh + cur + boff;
    s8v af[4], bf[4];
#pragma unroll
    for (int mi = 0; mi < 4; mi++) af[mi] = *(const s8v*)(Ab + mi * 512);
#pragma unroll
    for (int ni = 0; ni < 4; ni++) bf[ni] = *(const s8v*)(Bb + ni * 512);
    if (t < NT - 3) {
      const int nb = ((t + 3) & 3) * 12288;
      gl_lds16(aSrc + kcol, sh + nb + w * 512);
      gl_lds16(bSrc0 + kcol, sh + nb + 4096 + w * 512);
      gl_lds16(bSrc1 + kcol, sh + nb + 8192 + w * 512);
      kcol += 32;
    }
    __builtin_amdgcn_s_setprio(1);
#pragma unroll
    for (int mi = 0; mi < 4; mi++)
#pragma unroll
      for (int ni = 0; ni < 4; ni++)
        acc[mi][ni] = mfma16(bf[ni], af[mi], acc[mi][ni]);
    __builtin_amdgcn_s_setprio(0);
    if (t < NT - 3)       asm volatile("s_waitcnt vmcnt(6)" ::: "memory");
    else if (t == NT - 3) asm volatile("s_waitcnt vmcnt(3)" ::: "memory");
    else if (t == NT - 2) asm volatile("s_waitcnt vmcnt(0)" ::: "memory");
    if (t != NT - 1) __builtin_amdgcn_s_barrier();
  }

  const long m0 = (long)bm * 128 + wm * 64;
  const long n0 = (long)bn * 256 + wn * 64;
#pragma unroll
  for (int mi = 0; mi < 4; mi++) {
    long row = m0 + mi * 16 + l15;
#pragma unroll
    for (int ni = 0; ni < 4; ni++) {
      long col = n0 + ni * 16 + quad * 4;
      float* p = Cv + row * ldc + col;
      if (MODE == STORE_F32) {
        *(f32x4*)p = acc[mi][ni];
      } else {
        f32x4 old = *(const f32x4*)p;
        old += acc[mi][ni];
        *(f32x4*)p = old;
      }
    }
  }
}

// ---------------- causal flash attention (MQA): K from proj, V from v_t (pre-transposed)
__global__ __launch_bounds__(256) void flash_k(const u16* __restrict__ proj,
                                               const u16* __restrict__ v_t,
                                               u16* __restrict__ ctx) {
  __shared__ u16 Kt[4 * 1024];
  __shared__ u16 Vx[8 * 512];
  __shared__ u16 Pw[4 * 512];
  const int qt = blockIdx.x, h = blockIdx.y, b = blockIdx.z;
  const int tid = threadIdx.x;
  const int w = tid >> 6, lane = tid & 63, quad = lane >> 4, l15 = lane & 15;
  const int qbase = qt * 64 + w * 16;

  s8v qf[4];
  {
    long rowQ = (long)b * 2048 + qbase + l15;
    const u16* qp = proj + rowQ * 18688 + h * 128 + quad * 8;
#pragma unroll
    for (int kk = 0; kk < 4; kk++) qf[kk] = *(const s8v*)(qp + kk * 32);
  }
  f32x4 o[8];
#pragma unroll
  for (int i = 0; i < 8; i++) o[i] = {0.f, 0.f, 0.f, 0.f};
  float m_i[4] = {-1e30f, -1e30f, -1e30f, -1e30f};
  float l_i[4] = {0.f, 0.f, 0.f, 0.f};

  const int srow = lane >> 2;
  const int sseg = ((lane & 3) ^ ((lane >> 3) & 3)) * 8;
  const int rseg = (quad ^ ((l15 >> 1) & 3)) * 8;

  const int nkb = 2 * qt + 2;
  for (int kb = 0; kb < nkb; kb++) {
    const int k0 = kb * 32;
    {
      long rK = (long)b * 2048 + k0;
#pragma unroll
      for (int h2 = 0; h2 < 2; h2++)
        gl_lds16(proj + (rK + h2 * 16 + srow) * 18688 + 2048 + w * 32 + sseg,
                 Kt + w * 1024 + h2 * 512);
#pragma unroll
      for (int h2 = 0; h2 < 2; h2++)
        gl_lds16(v_t + ((long)b * 128 + w * 32 + h2 * 16 + srow) * 2048 + k0 + sseg,
                 Vx + (w * 2 + h2) * 512);
    }
    __syncthreads();
    if (k0 <= qbase + 15) {
      f32x4 s[2];
#pragma unroll
      for (int ni = 0; ni < 2; ni++) {
        f32x4 a = {0.f, 0.f, 0.f, 0.f};
#pragma unroll
        for (int kk = 0; kk < 4; kk++) {
          s8v kf = *(const s8v*)(Kt + kk * 1024 + (ni * 16 + l15) * 32 + rseg);
          a = mfma16(qf[kk], kf, a);
        }
        s[ni] = a;
      }
#pragma unroll
      for (int ni = 0; ni < 2; ni++) {
        int kg = k0 + ni * 16 + l15;
#pragma unroll
        for (int r = 0; r < 4; r++)
          if (kg > qbase + quad * 4 + r) s[ni][r] = -1e30f;
      }
      float al[4];
#pragma unroll
      for (int r = 0; r < 4; r++) {
        float mx = fmaxf(s[0][r], s[1][r]);
#pragma unroll
        for (int off = 8; off > 0; off >>= 1)
          mx = fmaxf(mx, __shfl_xor(mx, off, 16));
        float mn = fmaxf(m_i[r], mx);
        al[r] = __expf(m_i[r] - mn);
        m_i[r] = mn;
      }
#pragma unroll
      for (int ni = 0; ni < 2; ni++)
#pragma unroll
        for (int r = 0; r < 4; r++) s[ni][r] = __expf(s[ni][r] - m_i[r]);
#pragma unroll
      for (int r = 0; r < 4; r++) {
        float rs = s[0][r] + s[1][r];
#pragma unroll
        for (int off = 8; off > 0; off >>= 1)
          rs += __shfl_xor(rs, off, 16);
        l_i[r] = l_i[r] * al[r] + rs;
      }
#pragma unroll
      for (int ni = 0; ni < 2; ni++)
#pragma unroll
        for (int r = 0; r < 4; r++) {
          int p = quad * 4 + r;
          int sg = ni * 2 + (l15 >> 3);
          int sp = sg ^ ((p >> 1) & 3);
          Pw[w * 512 + p * 32 + sp * 8 + (l15 & 7)] = f2bf(s[ni][r]);
        }
      __asm__ volatile("s_waitcnt lgkmcnt(0)" ::: "memory");
#pragma unroll
      for (int nt = 0; nt < 8; nt++)
#pragma unroll
        for (int r = 0; r < 4; r++) o[nt][r] *= al[r];
      s8v pf = *(const s8v*)(Pw + w * 512 + l15 * 32 + rseg);
#pragma unroll
      for (int nt = 0; nt < 8; nt++) {
        s8v vf = *(const s8v*)(Vx + (nt * 16 + l15) * 32 + rseg);
        o[nt] = mfma16(pf, vf, o[nt]);
      }
    }
    __syncthreads();
  }
  float inv[4];
#pragma unroll
  for (int r = 0; r < 4; r++) inv[r] = 1.f / l_i[r];
#pragma unroll
  for (int nt = 0; nt < 8; nt++)
#pragma unroll
    for (int r = 0; r < 4; r++) {
      long row = (long)b * 2048 + qbase + quad * 4 + r;
      ctx[row * 2080 + h * 128 + nt * 16 + l15] = f2bf(o[nt][r] * inv[r]);
    }
}

// ---------------- workspace layout (bytes)
// wf_t is dead after the big GEMM -> its region is reused for ctx_aug.
#define OFF_WF   0L                       // wf_t 18688x2112 bf16 = 78,938,112 ; later ctx_aug (17,039,360)
#define OFF_WO   78938112L                // wo_t 2048x2080 bf16  =  8,519,680
#define OFF_WFF  87457792L                // wff_t 2048x8192 bf16 = 33,554,432
#define OFF_XN   121012224L               // xn_aug 4096x2112 bf16 = 17,301,504 (reused as v_t)
#define OFF_PROJ 138313728L               // proj 4096x18688 bf16 = 153,092,096
#define WS_NEED  291405824L

extern "C" void kernel_launch(void* const* d_in, const int* in_sizes, int n_in,
                              void* d_out, int out_size, void* d_ws, size_t ws_size,
                              hipStream_t stream) {
  const float* x       = (const float*)d_in[0];
  const float* gamma   = (const float*)d_in[1];
  const float* w_fused = (const float*)d_in[2];
  const float* w_attn  = (const float*)d_in[3];
  const float* w_ff    = (const float*)d_in[4];
  const float* a_q = (const float*)d_in[5];
  const float* b_q = (const float*)d_in[6];
  const float* a_k = (const float*)d_in[7];
  const float* b_k = (const float*)d_in[8];
  const float* a_v = (const float*)d_in[9];
  const float* b_v = (const float*)d_in[10];
  const float* a_o = (const float*)d_in[11];
  const float* b_o = (const float*)d_in[12];
  float* out = (float*)d_out;
  if (ws_size < (size_t)WS_NEED) return;

  char* ws = (char*)d_ws;
  u16* wf_t    = (u16*)(ws + OFF_WF);
  u16* ctx_aug = (u16*)(ws + OFF_WF);  // reuses wf_t region after big GEMM
  u16* wo_t    = (u16*)(ws + OFF_WO);
  u16* wff_t   = (u16*)(ws + OFF_WFF);
  u16* xn_aug  = (u16*)(ws + OFF_XN);
  u16* v_t     = (u16*)(ws + OFF_XN);  // reuses xn_aug region after big GEMM
  u16* proj    = (u16*)(ws + OFF_PROJ);

  dim3 tb(32, 8);
  transpose_cvt<<<dim3(18688 / 32, 2048 / 32), tb, 0, stream>>>(w_fused, wf_t, 2048, 18688, 2112);
  transpose_cvt<<<dim3(2048 / 32, 2048 / 32), tb, 0, stream>>>(w_attn, wo_t, 2048, 2048, 2080);
  transpose_cvt<<<dim3(2048 / 32, 8192 / 32), tb, 0, stream>>>(w_ff, wff_t, 8192, 2048, 8192);
  fill_aug_k<<<(18688 * 64 + 255) / 256, 256, 0, stream>>>(wf_t, 18688, 2112, 64, b_q, b_k, b_v);
  fill_aug_k<<<(2048 * 32 + 255) / 256, 256, 0, stream>>>(wo_t, 2048, 2080, 32, b_o, nullptr, nullptr);

  layernorm_k<<<4096, 256, 0, stream>>>(x, gamma, xn_aug);
  lora_down_x<<<4096, 256, 0, stream>>>(xn_aug, a_q, a_k, a_v);

  // proj = xn_aug @ wf_t^T  (q|k|v|x1|gate with QKV-LoRA folded into K-aug, K padded to 2112)
  gemm256_bt<<<dim3(16 * (18688 / 256)), 512, 0, stream>>>(xn_aug, wf_t, proj);

  rope_k<<<(4096 * 17 * 64) / 256, 256, 0, stream>>>(proj);
  silu_mul_k<<<(4096 * 1024) / 256, 256, 0, stream>>>(proj);
  vtrans<<<dim3(64, 4, 2), tb, 0, stream>>>(proj, v_t);

  flash_k<<<dim3(32, 16, 2), 256, 0, stream>>>(proj, v_t, ctx_aug);
  lora_down_ctx<<<4096, 256, 0, stream>>>(ctx_aug, a_o);

  // d_out = ctx_aug @ wo_t^T (o-LoRA folded), then += h @ wff_t^T
  gemm_out<STORE_F32><<<dim3(256), 512, 0, stream>>>(
      ctx_aug, 2080, wo_t, 2080, out, 2048, 2080);
  gemm_out<ADD_F32><<<dim3(256), 512, 0, stream>>>(
      proj + 2304, 18688, wff_t, 8192, out, 2048, 8192);
}